// Round 6
// baseline (11799.973 us; speedup 1.0000x reference)
//
#include <hip/hip_runtime.h>
#include <cstdint>
#include <cstddef>

#define NT 2048   // timesteps
#define NB 64     // batch
#define NH 256    // hidden
#define NG 768    // 3*NH
#define NL 3      // layers
#define CHUNK 128 // timesteps per chunk
#define NCH (NT / CHUNK)

typedef _Float16 h2 __attribute__((ext_vector_type(2)));
typedef _Float16 f16x8 __attribute__((ext_vector_type(8)));
typedef float f32x4 __attribute__((ext_vector_type(4)));
union HU { unsigned int u; h2 h; };

__device__ __forceinline__ float sigf(float x) {
    return 1.0f / (1.0f + __expf(-x));
}
__device__ __forceinline__ float tanhfast(float x) {
    float e = __expf(2.0f * x);
    return 1.0f - 2.0f / (e + 1.0f);
}

// 4x fdot2: acc += sum over 8 f16 pairs packed in wv (weights) * hv (h)
__device__ __forceinline__ float dot8(uint4 wv, uint4 hv, float acc) {
#if __has_builtin(__builtin_amdgcn_fdot2)
    HU a, b;
    a.u = wv.x; b.u = hv.x; acc = __builtin_amdgcn_fdot2(a.h, b.h, acc, false);
    a.u = wv.y; b.u = hv.y; acc = __builtin_amdgcn_fdot2(a.h, b.h, acc, false);
    a.u = wv.z; b.u = hv.z; acc = __builtin_amdgcn_fdot2(a.h, b.h, acc, false);
    a.u = wv.w; b.u = hv.w; acc = __builtin_amdgcn_fdot2(a.h, b.h, acc, false);
#else
    HU a, b;
    const unsigned int wu[4] = {wv.x, wv.y, wv.z, wv.w};
    const unsigned int hu[4] = {hv.x, hv.y, hv.z, hv.w};
#pragma unroll
    for (int i = 0; i < 4; ++i) {
        a.u = wu[i]; b.u = hu[i];
        acc = fmaf((float)a.h[0], (float)b.h[0], acc);
        acc = fmaf((float)a.h[1], (float)b.h[1], acc);
    }
#endif
    return acc;
}

// ---------------------------------------------------------------------------
// Repack W_hh (fp32 [3][768][256]) for the 1024-thread 4-way-split scan.
// Thread t owns col=t>>2, kq=t&3 (64 K-elems). Chunk c = g*8+cc (g=gate,
// cc=0..7): elems W[l][g*256+col][kq*64 + cc*8 .. +7], at wp[l][c*1024+t].
// ---------------------------------------------------------------------------
__global__ void repack_whh(const float* __restrict__ whh, uint4* __restrict__ wp) {
    int idx = blockIdx.x * 256 + threadIdx.x;     // uint4 index, total 73728
    if (idx >= NL * 24 * 1024) return;
    int t  = idx & 1023;
    int c  = (idx >> 10) % 24;
    int l  = idx / (24 * 1024);
    int g  = c >> 3, cc = c & 7;
    int col = t >> 2, kq = t & 3;
    const float* row = whh + ((size_t)(l * NG + g * NH + col)) * NH + kq * 64 + cc * 8;
    HU u0, u1, u2, u3;
    u0.h = h2{(_Float16)row[0], (_Float16)row[1]};
    u1.h = h2{(_Float16)row[2], (_Float16)row[3]};
    u2.h = h2{(_Float16)row[4], (_Float16)row[5]};
    u3.h = h2{(_Float16)row[6], (_Float16)row[7]};
    wp[idx] = uint4{u0.u, u1.u, u2.u, u3.u};
}

// ---------------------------------------------------------------------------
// fp32 -> fp16 cast (vectorized, exact element count = n4*4)
// ---------------------------------------------------------------------------
__global__ void cast_f32_f16(const float* __restrict__ in, _Float16* __restrict__ outp,
                             int n4) {
    int i = blockIdx.x * 256 + threadIdx.x;
    if (i >= n4) return;
    float4 v = ((const float4*)in)[i];
    h2 a = {(_Float16)v.x, (_Float16)v.y};
    h2 b = {(_Float16)v.z, (_Float16)v.w};
    HU ua, ub; ua.h = a; ub.h = b;
    ((uint2*)outp)[i] = uint2{ua.u, ub.u};
}

// ---------------------------------------------------------------------------
// gi[M,768] = A[M,256](f16) @ W[768,256](f16)^T + bias(f32), via
// mfma_f32_16x16x32_f16, fragments loaded directly from global (k-contiguous
// 16B per lane; W/A rows are L1/L2-hot). Block=256thr/4 waves; wave w owns
// m-tile (by*64 + w*16), n-tiles bx*64 + {0,16,32,48}. Grid (12, M/64).
// ---------------------------------------------------------------------------
__global__ __launch_bounds__(256) void gemm_gi(const _Float16* __restrict__ A,
                                               const _Float16* __restrict__ W,
                                               const float* __restrict__ bias,
                                               float* __restrict__ C) {
    const int lane = threadIdx.x & 63;
    const int wv   = threadIdx.x >> 6;
    const int m0   = (blockIdx.y << 6) + (wv << 4);
    const int n0   = blockIdx.x << 6;
    const int r    = lane & 15;
    const int ko   = (lane >> 4) << 3;           // 0,8,16,24

    const _Float16* arow = A + (size_t)(m0 + r) * NH + ko;
    const _Float16* wrow = W + (size_t)(n0 + r) * NH + ko;

    f32x4 acc0 = {0,0,0,0}, acc1 = {0,0,0,0}, acc2 = {0,0,0,0}, acc3 = {0,0,0,0};
#pragma unroll
    for (int k0 = 0; k0 < 8; ++k0) {
        const f16x8 af = *(const f16x8*)(arow + k0 * 32);
        const f16x8 b0 = *(const f16x8*)(wrow + k0 * 32);
        const f16x8 b1 = *(const f16x8*)(wrow + 16 * NH + k0 * 32);
        const f16x8 b2 = *(const f16x8*)(wrow + 32 * NH + k0 * 32);
        const f16x8 b3 = *(const f16x8*)(wrow + 48 * NH + k0 * 32);
        acc0 = __builtin_amdgcn_mfma_f32_16x16x32_f16(af, b0, acc0, 0, 0, 0);
        acc1 = __builtin_amdgcn_mfma_f32_16x16x32_f16(af, b1, acc1, 0, 0, 0);
        acc2 = __builtin_amdgcn_mfma_f32_16x16x32_f16(af, b2, acc2, 0, 0, 0);
        acc3 = __builtin_amdgcn_mfma_f32_16x16x32_f16(af, b3, acc3, 0, 0, 0);
    }

    // C/D layout: col = lane&15, row = (lane>>4)*4 + reg  [m89 verified]
    const int rowb = m0 + ((lane >> 4) << 2);
    const f32x4 av[4] = {acc0, acc1, acc2, acc3};
#pragma unroll
    for (int j = 0; j < 4; ++j) {
        const int col = n0 + (j << 4) + r;
        const float bb = bias[col];
#pragma unroll
        for (int q = 0; q < 4; ++q)
            C[(size_t)(rowb + q) * NG + col] = av[j][q] + bb;
    }
}

// ---------------------------------------------------------------------------
// 4-way-split register-resident GRU scan. 1024 threads/block, one block per
// batch element. Thread t: col=t>>2, kq=t&3; 24 uint4 (96 VGPR) fp16 weights
// (3 gate rows x K-quarter). Full dot via shfl_xor(1)+shfl_xor(2). h fp32 in
// register; fp16 copy double-buffered in LDS, quarters padded to 144B stride
// (banks 4kq+4cc -> conflict-free). One barrier per step.
// ---------------------------------------------------------------------------
__global__ __launch_bounds__(1024, 4) void gru_scan(const float* __restrict__ gi,
                                                    const uint4* __restrict__ wp,
                                                    const float* __restrict__ bh,
                                                    float* __restrict__ hst,
                                                    _Float16* __restrict__ outf,
                                                    float* __restrict__ outl,
                                                    int steps) {
    const int b   = blockIdx.x;
    const int t   = threadIdx.x;
    const int col = t >> 2;
    const int kq  = t & 3;
    const bool own = (kq == 0);
    __shared__ __align__(16) unsigned char hraw[2][576];   // 4 quarters x 144B

    uint4 w[24];
#pragma unroll
    for (int c = 0; c < 24; ++c) w[c] = wp[c * 1024 + t];

    float h = hst[b * NH + col];
    const float bhr = bh[col];
    const float bhz = bh[NH + col];
    const float bhn = bh[2 * NH + col];

    if (own) *(_Float16*)&hraw[0][(col >> 6) * 144 + (col & 63) * 2] = (_Float16)h;
    __syncthreads();

    const float* g0 = gi + (size_t)b * NG;
    float gr = g0[col], gz = g0[NH + col], gn = g0[2 * NH + col];

    int p = 0;
    for (int st = 0; st < steps; ++st) {
        const int stq = (st + 1 < steps) ? (st + 1) : st;
        const float* gq = gi + ((size_t)stq * NB + b) * NG;
        const float pr = gq[col], pz = gq[NH + col], pn = gq[2 * NH + col];

        const uint4* hv = (const uint4*)&hraw[p][kq * 144];  // my K-quarter
        float a0 = 0.0f, a1 = 0.0f, a2 = 0.0f;
#pragma unroll
        for (int cc = 0; cc < 8; ++cc) {
            const uint4 hh = hv[cc];
            a0 = dot8(w[cc],      hh, a0);   // r row
            a1 = dot8(w[8 + cc],  hh, a1);   // z row
            a2 = dot8(w[16 + cc], hh, a2);   // n row
        }
        a0 += __shfl_xor(a0, 1); a0 += __shfl_xor(a0, 2);
        a1 += __shfl_xor(a1, 1); a1 += __shfl_xor(a1, 2);
        a2 += __shfl_xor(a2, 1); a2 += __shfl_xor(a2, 2);

        const float r = sigf(gr + a0 + bhr);
        const float z = sigf(gz + a1 + bhz);
        const float n = tanhfast(gn + r * (a2 + bhn));
        h = (1.0f - z) * n + z * h;

        if (own) {
            *(_Float16*)&hraw[p ^ 1][(col >> 6) * 144 + (col & 63) * 2] = (_Float16)h;
            if (outf) outf[((size_t)st * NB + b) * NH + col] = (_Float16)h;
        }
        gr = pr; gz = pz; gn = pn;
        p ^= 1;
        __syncthreads();
    }

    if (own) {
        hst[b * NH + col] = h;
        if (outl) outl[b * NH + col] = h;
    }
}

// ---------------------------------------------------------------------------
extern "C" void kernel_launch(void* const* d_in, const int* in_sizes, int n_in,
                              void* d_out, int out_size, void* d_ws, size_t ws_size,
                              hipStream_t stream) {
    const float* x   = (const float*)d_in[0];   // [2048,64,256]
    const float* Wih = (const float*)d_in[1];   // [3,768,256]
    const float* Whh = (const float*)d_in[2];   // [3,768,256]
    const float* bih = (const float*)d_in[3];   // [3,768]
    const float* bhh = (const float*)d_in[4];   // [3,768]
    float* out = (float*)d_out;                 // [64,256]

    // workspace layout (all offsets 16B-aligned) — total ~40.3 MB
    uint4*     wpack = (uint4*)d_ws;                                  // 73728 u4   1.18 MB
    float*     gi    = (float*)(wpack + NL * 24 * 1024);              // 6,291,456  25.2 MB
    float*     hst   = gi + (size_t)CHUNK * NB * NG;                  // 49,152     0.20 MB
    _Float16*  xh    = (_Float16*)(hst + (size_t)NL * NB * NH);       // 2,097,152  4.2 MB
    _Float16*  obA   = xh + (size_t)CHUNK * NB * NH;                  // 2,097,152  4.2 MB
    _Float16*  obB   = obA + (size_t)CHUNK * NB * NH;                 // 2,097,152  4.2 MB
    _Float16*  wihh  = obB + (size_t)CHUNK * NB * NH;                 // 589,824    1.18 MB

    hipMemsetAsync(hst, 0, (size_t)NL * NB * NH * sizeof(float), stream);
    repack_whh<<<288, 256, 0, stream>>>(Whh, wpack);
    cast_f32_f16<<<576, 256, 0, stream>>>(Wih, wihh, NL * NG * NH / 4);

    for (int c = 0; c < NCH; ++c) {
        cast_f32_f16<<<2048, 256, 0, stream>>>(
            x + (size_t)c * CHUNK * NB * NH, xh, CHUNK * NB * NH / 4);
        for (int l = 0; l < NL; ++l) {
            const _Float16* A = (l == 0) ? xh : ((l == 1) ? obA : obB);
            gemm_gi<<<dim3(12, CHUNK * NB / 64), 256, 0, stream>>>(
                A, wihh + (size_t)l * NG * NH, bih + (size_t)l * NG, gi);
            _Float16* outf = (l == 0) ? obA : ((l == 1) ? obB : nullptr);
            float* outl = (l == 2 && c == NCH - 1) ? out : nullptr;
            gru_scan<<<NB, 1024, 0, stream>>>(
                gi, wpack + (size_t)l * 24 * 1024, bhh + (size_t)l * NG,
                hst + (size_t)l * NB * NH, outf, outl, CHUNK);
        }
    }
}

// Round 7
// 9234.673 us; speedup vs baseline: 1.2778x; 1.2778x over previous
//
#include <hip/hip_runtime.h>
#include <cstdint>
#include <cstddef>

#define NT 2048   // timesteps
#define NB 64     // batch
#define NH 256    // hidden
#define NG 768    // 3*NH
#define NL 3      // layers
#define CHUNK 128 // timesteps per chunk
#define NCH (NT / CHUNK)

typedef _Float16 h2 __attribute__((ext_vector_type(2)));
typedef _Float16 f16x8 __attribute__((ext_vector_type(8)));
typedef float f32x4 __attribute__((ext_vector_type(4)));
union HU { unsigned int u; h2 h; };

__device__ __forceinline__ float sigf(float x) {
    return 1.0f / (1.0f + __expf(-x));
}
__device__ __forceinline__ float tanhfast(float x) {
    float e = __expf(2.0f * x);
    return 1.0f - 2.0f / (e + 1.0f);
}

// 4x fdot2: acc += sum over 8 f16 pairs packed in wv (weights) * hv (h)
__device__ __forceinline__ float dot8(uint4 wv, uint4 hv, float acc) {
#if __has_builtin(__builtin_amdgcn_fdot2)
    HU a, b;
    a.u = wv.x; b.u = hv.x; acc = __builtin_amdgcn_fdot2(a.h, b.h, acc, false);
    a.u = wv.y; b.u = hv.y; acc = __builtin_amdgcn_fdot2(a.h, b.h, acc, false);
    a.u = wv.z; b.u = hv.z; acc = __builtin_amdgcn_fdot2(a.h, b.h, acc, false);
    a.u = wv.w; b.u = hv.w; acc = __builtin_amdgcn_fdot2(a.h, b.h, acc, false);
#else
    HU a, b;
    const unsigned int wu[4] = {wv.x, wv.y, wv.z, wv.w};
    const unsigned int hu[4] = {hv.x, hv.y, hv.z, hv.w};
#pragma unroll
    for (int i = 0; i < 4; ++i) {
        a.u = wu[i]; b.u = hu[i];
        acc = fmaf((float)a.h[0], (float)b.h[0], acc);
        acc = fmaf((float)a.h[1], (float)b.h[1], acc);
    }
#endif
    return acc;
}

// ---------------------------------------------------------------------------
// Repack W_hh (fp32 [3][768][256]) for the 512-thread 2-way-split scan.
// Thread t owns col=t>>1, kh=t&1 (128 K-elems). Chunk c = g*16+cc:
// elems W[l][g*256+col][kh*128 + cc*8 .. +7], stored at wp[l][c*512 + t].
// ---------------------------------------------------------------------------
__global__ void repack_whh(const float* __restrict__ whh, uint4* __restrict__ wp) {
    int idx = blockIdx.x * 256 + threadIdx.x;     // uint4 index, total 73728
    if (idx >= NL * 48 * 512) return;
    int t  = idx & 511;
    int c  = (idx >> 9) % 48;
    int l  = idx / (48 * 512);
    int g  = c >> 4, cc = c & 15;
    int col = t >> 1, kh = t & 1;
    const float* row = whh + ((size_t)(l * NG + g * NH + col)) * NH + kh * 128 + cc * 8;
    HU u0, u1, u2, u3;
    u0.h = h2{(_Float16)row[0], (_Float16)row[1]};
    u1.h = h2{(_Float16)row[2], (_Float16)row[3]};
    u2.h = h2{(_Float16)row[4], (_Float16)row[5]};
    u3.h = h2{(_Float16)row[6], (_Float16)row[7]};
    wp[idx] = uint4{u0.u, u1.u, u2.u, u3.u};
}

// ---------------------------------------------------------------------------
// fp32 -> fp16 cast (vectorized, exact element count = n4*4)
// ---------------------------------------------------------------------------
__global__ void cast_f32_f16(const float* __restrict__ in, _Float16* __restrict__ outp,
                             int n4) {
    int i = blockIdx.x * 256 + threadIdx.x;
    if (i >= n4) return;
    float4 v = ((const float4*)in)[i];
    h2 a = {(_Float16)v.x, (_Float16)v.y};
    h2 b = {(_Float16)v.z, (_Float16)v.w};
    HU ua, ub; ua.h = a; ub.h = b;
    ((uint2*)outp)[i] = uint2{ua.u, ub.u};
}

// ---------------------------------------------------------------------------
// gi[M,768] = A[M,256](f16) @ W[768,256](f16)^T + bias(f32), via
// mfma_f32_16x16x32_f16, fragments loaded directly from global.
// ---------------------------------------------------------------------------
__global__ __launch_bounds__(256) void gemm_gi(const _Float16* __restrict__ A,
                                               const _Float16* __restrict__ W,
                                               const float* __restrict__ bias,
                                               float* __restrict__ C) {
    const int lane = threadIdx.x & 63;
    const int wv   = threadIdx.x >> 6;
    const int m0   = (blockIdx.y << 6) + (wv << 4);
    const int n0   = blockIdx.x << 6;
    const int r    = lane & 15;
    const int ko   = (lane >> 4) << 3;           // 0,8,16,24

    const _Float16* arow = A + (size_t)(m0 + r) * NH + ko;
    const _Float16* wrow = W + (size_t)(n0 + r) * NH + ko;

    f32x4 acc0 = {0,0,0,0}, acc1 = {0,0,0,0}, acc2 = {0,0,0,0}, acc3 = {0,0,0,0};
#pragma unroll
    for (int k0 = 0; k0 < 8; ++k0) {
        const f16x8 af = *(const f16x8*)(arow + k0 * 32);
        const f16x8 b0 = *(const f16x8*)(wrow + k0 * 32);
        const f16x8 b1 = *(const f16x8*)(wrow + 16 * NH + k0 * 32);
        const f16x8 b2 = *(const f16x8*)(wrow + 32 * NH + k0 * 32);
        const f16x8 b3 = *(const f16x8*)(wrow + 48 * NH + k0 * 32);
        acc0 = __builtin_amdgcn_mfma_f32_16x16x32_f16(af, b0, acc0, 0, 0, 0);
        acc1 = __builtin_amdgcn_mfma_f32_16x16x32_f16(af, b1, acc1, 0, 0, 0);
        acc2 = __builtin_amdgcn_mfma_f32_16x16x32_f16(af, b2, acc2, 0, 0, 0);
        acc3 = __builtin_amdgcn_mfma_f32_16x16x32_f16(af, b3, acc3, 0, 0, 0);
    }

    // C/D layout: col = lane&15, row = (lane>>4)*4 + reg  [m89 verified]
    const int rowb = m0 + ((lane >> 4) << 2);
    const f32x4 av[4] = {acc0, acc1, acc2, acc3};
#pragma unroll
    for (int j = 0; j < 4; ++j) {
        const int col = n0 + (j << 4) + r;
        const float bb = bias[col];
#pragma unroll
        for (int q = 0; q < 4; ++q)
            C[(size_t)(rowb + q) * NG + col] = av[j][q] + bb;
    }
}

// ---------------------------------------------------------------------------
// 2-way-split register-resident GRU scan. 512 threads/block, one block per
// batch element. Thread t: col=t>>1, kh=t&1. 48 NAMED uint4 (192 VGPR) of
// fp16 weights -- named scalars, not an array, so the compiler's
// array->AGPR heuristic doesn't fire; __launch_bounds__(512,2) gives a
// 256-reg/wave budget. Full dot via shfl_xor(1). h fp32 in register; fp16
// copy double-buffered in LDS, K-halves at 272B stride (banks differ by 4
// -> conflict-free broadcast). One barrier per step.
// ---------------------------------------------------------------------------
#define LW(i) uint4 w##i = wp[(i) * 512 + t];
#define DOT3(cc, wr, wz, wn) { const uint4 hh = hv4[cc];      \
        a0 = dot8(wr, hh, a0);                                \
        a1 = dot8(wz, hh, a1);                                \
        a2 = dot8(wn, hh, a2); }

__global__ __launch_bounds__(512, 2) void gru_scan(const float* __restrict__ gi,
                                                   const uint4* __restrict__ wp,
                                                   const float* __restrict__ bh,
                                                   float* __restrict__ hst,
                                                   _Float16* __restrict__ outf,
                                                   float* __restrict__ outl,
                                                   int steps) {
    const int b   = blockIdx.x;
    const int t   = threadIdx.x;
    const int col = t >> 1;
    const int kh  = t & 1;
    const bool own = (kh == 0);
    __shared__ __align__(16) unsigned char hraw[2][544];   // 2 K-halves x 272B

    // 48 named weight chunks (192 VGPRs), coalesced loads
    LW(0)  LW(1)  LW(2)  LW(3)  LW(4)  LW(5)  LW(6)  LW(7)
    LW(8)  LW(9)  LW(10) LW(11) LW(12) LW(13) LW(14) LW(15)
    LW(16) LW(17) LW(18) LW(19) LW(20) LW(21) LW(22) LW(23)
    LW(24) LW(25) LW(26) LW(27) LW(28) LW(29) LW(30) LW(31)
    LW(32) LW(33) LW(34) LW(35) LW(36) LW(37) LW(38) LW(39)
    LW(40) LW(41) LW(42) LW(43) LW(44) LW(45) LW(46) LW(47)

    float h = hst[b * NH + col];
    const float bhr = bh[col];
    const float bhz = bh[NH + col];
    const float bhn = bh[2 * NH + col];

    // h[col] lives in K-half (col>>7), slot (col&127)
    const int hoff = (col >> 7) * 272 + (col & 127) * 2;
    if (own) *(_Float16*)&hraw[0][hoff] = (_Float16)h;
    __syncthreads();

    const float* g0 = gi + (size_t)b * NG;
    float gr = g0[col], gz = g0[NH + col], gn = g0[2 * NH + col];

    int p = 0;
    for (int st = 0; st < steps; ++st) {
        const int stq = (st + 1 < steps) ? (st + 1) : st;
        const float* gq = gi + ((size_t)stq * NB + b) * NG;
        const float pr = gq[col], pz = gq[NH + col], pn = gq[2 * NH + col];

        const uint4* hv4 = (const uint4*)&hraw[p][kh * 272];  // my K-half
        float a0 = 0.0f, a1 = 0.0f, a2 = 0.0f;
        DOT3(0,  w0,  w16, w32)  DOT3(1,  w1,  w17, w33)
        DOT3(2,  w2,  w18, w34)  DOT3(3,  w3,  w19, w35)
        DOT3(4,  w4,  w20, w36)  DOT3(5,  w5,  w21, w37)
        DOT3(6,  w6,  w22, w38)  DOT3(7,  w7,  w23, w39)
        DOT3(8,  w8,  w24, w40)  DOT3(9,  w9,  w25, w41)
        DOT3(10, w10, w26, w42)  DOT3(11, w11, w27, w43)
        DOT3(12, w12, w28, w44)  DOT3(13, w13, w29, w45)
        DOT3(14, w14, w30, w46)  DOT3(15, w15, w31, w47)

        a0 += __shfl_xor(a0, 1);
        a1 += __shfl_xor(a1, 1);
        a2 += __shfl_xor(a2, 1);

        const float r = sigf(gr + a0 + bhr);
        const float z = sigf(gz + a1 + bhz);
        const float n = tanhfast(gn + r * (a2 + bhn));
        h = (1.0f - z) * n + z * h;

        if (own) {
            *(_Float16*)&hraw[p ^ 1][hoff] = (_Float16)h;   // other buffer: no WAR
            if (outf) outf[((size_t)st * NB + b) * NH + col] = (_Float16)h;
        }
        gr = pr; gz = pz; gn = pn;
        p ^= 1;
        __syncthreads();
    }

    if (own) {
        hst[b * NH + col] = h;
        if (outl) outl[b * NH + col] = h;
    }
}

// ---------------------------------------------------------------------------
extern "C" void kernel_launch(void* const* d_in, const int* in_sizes, int n_in,
                              void* d_out, int out_size, void* d_ws, size_t ws_size,
                              hipStream_t stream) {
    const float* x   = (const float*)d_in[0];   // [2048,64,256]
    const float* Wih = (const float*)d_in[1];   // [3,768,256]
    const float* Whh = (const float*)d_in[2];   // [3,768,256]
    const float* bih = (const float*)d_in[3];   // [3,768]
    const float* bhh = (const float*)d_in[4];   // [3,768]
    float* out = (float*)d_out;                 // [64,256]

    // workspace layout (all offsets 16B-aligned) — total ~40.3 MB
    uint4*     wpack = (uint4*)d_ws;                                  // 73728 u4   1.18 MB
    float*     gi    = (float*)(wpack + NL * 48 * 512);               // 6,291,456  25.2 MB
    float*     hst   = gi + (size_t)CHUNK * NB * NG;                  // 49,152     0.20 MB
    _Float16*  xh    = (_Float16*)(hst + (size_t)NL * NB * NH);       // 2,097,152  4.2 MB
    _Float16*  obA   = xh + (size_t)CHUNK * NB * NH;                  // 2,097,152  4.2 MB
    _Float16*  obB   = obA + (size_t)CHUNK * NB * NH;                 // 2,097,152  4.2 MB
    _Float16*  wihh  = obB + (size_t)CHUNK * NB * NH;                 // 589,824    1.18 MB

    hipMemsetAsync(hst, 0, (size_t)NL * NB * NH * sizeof(float), stream);
    repack_whh<<<288, 256, 0, stream>>>(Whh, wpack);
    cast_f32_f16<<<576, 256, 0, stream>>>(Wih, wihh, NL * NG * NH / 4);

    for (int c = 0; c < NCH; ++c) {
        cast_f32_f16<<<2048, 256, 0, stream>>>(
            x + (size_t)c * CHUNK * NB * NH, xh, CHUNK * NB * NH / 4);
        for (int l = 0; l < NL; ++l) {
            const _Float16* A = (l == 0) ? xh : ((l == 1) ? obA : obB);
            gemm_gi<<<dim3(12, CHUNK * NB / 64), 256, 0, stream>>>(
                A, wihh + (size_t)l * NG * NH, bih + (size_t)l * NG, gi);
            _Float16* outf = (l == 0) ? obA : ((l == 1) ? obB : nullptr);
            float* outl = (l == 2 && c == NCH - 1) ? out : nullptr;
            gru_scan<<<NB, 512, 0, stream>>>(
                gi, wpack + (size_t)l * 48 * 512, bhh + (size_t)l * NG,
                hst + (size_t)l * NB * NH, outf, outl, CHUNK);
        }
    }
}